// Round 6
// baseline (130.293 us; speedup 1.0000x reference)
//
#include <hip/hip_runtime.h>
#include <hip/hip_fp16.h>

// PairwiseMamba: 2304 independent mamba scans (T=1024, d_inner=4, d_state=8).
// R5: fix the scratch spill. Empirically the compiler caps VGPRs at
// ~256/min_waves (granule 8): launch_bounds(*,6) -> 40 VGPR + per-thread
// scratch (the 6-14MB WRITE_SIZE of R2-R4) + scratch-capped residency.
// launch_bounds(256,4) -> 64-VGPR cap, which this footprint fits (R1: 52).
// Also: DT+DS merged into one 8B record [d][t]=(fp32 dt, half2(dtx,sz)),
// row stride 66 uints -> scan = 2 LDS reads/iter (b64+b32), conflict-free:
//   write: 4x lane-consecutive ds_write_b64; read: 4 addrs/half at banks
//   {0,2,4,6}+2*t2 (disjoint, 8-way broadcast); halves destaggered 16 banks.
// BC[s][t] half2(B,C) stride 33 unchanged. LDS 16.9KB -> 8 blocks/CU cap.

typedef float v2f __attribute__((ext_vector_type(2)));

#define TT 1024
#define TC 32
#define GSEG 4
#define SEGLEN (TT / GSEG)             // 256
#define NCHUNK (SEGLEN / TC)           // 8
#define NUM_PAIRS 36
#define NSEQ 2304

// per-half staging (uint slots): DTDS [0,264) rows of 66 per d; BC [264,528)
#define DTDS_STRIDE 66                 // uints per d-row (64 data + 2 pad)
#define BC_OFF 264
#define BC_STRIDE 33                   // half2 slots per BC row
#define PER_HALF_STRIDE 528            // floats; %32==16 -> halves bank-disjoint
#define PER_WAVE (2 * PER_HALF_STRIDE) // 1056 floats
#define STAGE_TOTAL (GSEG * PER_WAVE)  // 4224 floats = 16896 B

__device__ __forceinline__ float fast_silu(float v) {
    float e = __builtin_amdgcn_exp2f(v * -1.4426950408889634f);
    return v * __builtin_amdgcn_rcpf(1.0f + e);
}
// softplus, direct form: log(1+exp(v)). Safe: |v| <~ 20 here.
__device__ __forceinline__ float fast_softplus(float v) {
    float e = __builtin_amdgcn_exp2f(v * 1.4426950408889634f);
    return __builtin_amdgcn_logf(1.0f + e) * 0.6931471805599453f;
}
__device__ __forceinline__ uint pk_h2(float a, float b) {
    return __builtin_bit_cast(uint, __builtin_amdgcn_cvt_pkrtz(a, b));
}

__global__ __launch_bounds__(256, 4)
void pm_kernel(const float* __restrict__ raw,        // (N,2,T)
               const float* __restrict__ in_proj_w,  // (8,2)
               const float* __restrict__ conv_w,     // (4,2)
               const float* __restrict__ conv_b,     // (4)
               const float* __restrict__ x_proj_w,   // (17,4)
               const float* __restrict__ dt_proj_w,  // (4,1)
               const float* __restrict__ dt_proj_b,  // (4)
               const float* __restrict__ A_log,      // (4,8)
               const float* __restrict__ D_skip,     // (4)
               const float* __restrict__ out_proj_w, // (2,4)
               const float* __restrict__ proj_w,     // (16,2)
               const float* __restrict__ proj_b,     // (16)
               float* __restrict__ out)              // (64,16), pre-zeroed
{
    __shared__ float lds[STAGE_TOTAL];

    const int tid  = threadIdx.x;
    const int wid  = tid >> 6;        // segment index g (0..3)
    const int lane = tid & 63;
    const int half = lane >> 5;       // which of the block's 2 sequences
    const int lh   = lane & 31;       // pointwise: t-in-chunk; scan: ds = d*8+s
    const int n    = blockIdx.x * 2 + half;
    const float* rp = raw + (size_t)n * (2 * TT);

    float* hb = lds + wid * PER_WAVE + half * PER_HALF_STRIDE;

    // ---- weights (wave-uniform -> scalarized) ----
    float ip0[8], ip1[8];
#pragma unroll
    for (int j = 0; j < 8; ++j) { ip0[j] = in_proj_w[2*j]; ip1[j] = in_proj_w[2*j+1]; }
    float cw0[4], cw1[4], cbv[4], dpw[4], dpb[4], Dsk[4], ow0[4], ow1[4], xp0[4];
#pragma unroll
    for (int d = 0; d < 4; ++d) {
        cw0[d] = conv_w[2*d]; cw1[d] = conv_w[2*d+1]; cbv[d] = conv_b[d];
        dpw[d] = dt_proj_w[d]; dpb[d] = dt_proj_b[d];
        Dsk[d] = D_skip[d]; ow0[d] = out_proj_w[d]; ow1[d] = out_proj_w[4+d];
        xp0[d] = x_proj_w[d];
    }
    v2f xbc[8][4];  // {x_proj_w[1+s][d], x_proj_w[9+s][d]}
#pragma unroll
    for (int s = 0; s < 8; ++s)
#pragma unroll
        for (int d = 0; d < 4; ++d)
            xbc[s][d] = (v2f){x_proj_w[4*(1+s) + d], x_proj_w[4*(9+s) + d]};

    const float LOG2E = 1.4426950408889634f;
    // scan-role constants: lane lh -> (d,s)
    const int   d_idx = lh >> 3;
    const int   s_idx = lh & 7;
    const float A2ds  = -__expf(A_log[lh]) * LOG2E;   // a = exp2(dt * A2ds)
    const float owd0  = out_proj_w[d_idx];
    const float owd1  = out_proj_w[4 + d_idx];

    // hoisted scan read pointers (imm offsets inside the loop)
    const uint2* ddp = (const uint2*)((uint*)hb + d_idx * DTDS_STRIDE); // [t2]
    const uint*  bcp = (const uint*)hb + BC_OFF + s_idx * BC_STRIDE;    // [t2]

    // segment-local affine reduction state (per ds lane)
    float A_run = 1.0f, hB = 0.0f, W = 0.0f, S = 0.0f;
    float sacc0 = 0.f, sacc1 = 0.f;                    // skip-term partials

    const int seg0 = wid * SEGLEN;

    // prefetch chunk 0 raw samples (t and t-1, both channels)
    int t0 = seg0 + lh;
    float c0  = rp[t0];
    float c1  = rp[TT + t0];
    float c0m = (t0 > 0) ? rp[t0 - 1]      : 0.0f;     // causal pad at t==0
    float c1m = (t0 > 0) ? rp[TT + t0 - 1] : 0.0f;

    for (int chunk = 0; chunk < NCHUNK; ++chunk) {
        // software prefetch next chunk's raw
        float p0 = 0.f, p1 = 0.f, p0m = 0.f, p1m = 0.f;
        if (chunk + 1 < NCHUNK) {
            int tn = seg0 + (chunk + 1) * TC + lh;     // tn >= 32 -> tn-1 valid
            p0  = rp[tn];       p1  = rp[TT + tn];
            p0m = rp[tn - 1];   p1m = rp[TT + tn - 1];
        }

        // ---- pointwise: this lane handles t = seg0 + chunk*TC + lh ----
        float x[4], sz[4];
#pragma unroll
        for (int d = 0; d < 4; ++d) {
            float xz  = ip0[d]*c0  + ip1[d]*c1;
            float xm1 = ip0[d]*c0m + ip1[d]*c1m;
            float zv  = ip0[4+d]*c0 + ip1[4+d]*c1;
            float v   = xm1*cw0[d] + xz*cw1[d] + cbv[d];   // causal conv k=2
            x[d]  = fast_silu(v);
            sz[d] = fast_silu(zv);
        }

        float dtin = xp0[0]*x[0] + xp0[1]*x[1] + xp0[2]*x[2] + xp0[3]*x[3];

        v2f bc[8];
#pragma unroll
        for (int s = 0; s < 8; ++s) {
            v2f a = xbc[s][0] * (v2f){x[0], x[0]};
            a = __builtin_elementwise_fma(xbc[s][1], (v2f){x[1], x[1]}, a);
            a = __builtin_elementwise_fma(xbc[s][2], (v2f){x[2], x[2]}, a);
            bc[s] = __builtin_elementwise_fma(xbc[s][3], (v2f){x[3], x[3]}, a);
        }

        float dt[4];
#pragma unroll
        for (int d = 0; d < 4; ++d) {
            dt[d] = fast_softplus(dtin*dpw[d] + dpb[d]);
            float g = x[d] * Dsk[d] * sz[d];               // skip term
            sacc0 = fmaf(g, ow0[d], sacc0);
            sacc1 = fmaf(g, ow1[d], sacc1);
        }

        // stage: DTDS 4x lane-consecutive b64; BC 8x lane-consecutive b32
        uint* dds = (uint*)hb + lh * 2;
#pragma unroll
        for (int d = 0; d < 4; ++d) {
            *(uint2*)(dds + d * DTDS_STRIDE) =
                make_uint2(__builtin_bit_cast(uint, dt[d]),
                           pk_h2(dt[d] * x[d], sz[d]));
        }
        uint* bcw = (uint*)hb + BC_OFF + lh;
#pragma unroll
        for (int s = 0; s < 8; ++s)
            bcw[s * BC_STRIDE] = pk_h2(bc[s].x, bc[s].y);

        // ---- scan: lane owns (d_idx, s_idx); local affine reduction ----
        // (same-wave LDS RAW: compiler orders via its own waitcnt insertion)
#pragma unroll
        for (int t2 = 0; t2 < TC; ++t2) {
            uint2 dd = ddp[t2];                             // (dt, half2(dtx,sz))
            uint  ubc = bcp[t2];                            // half2(B, C)
            float dtv = __builtin_bit_cast(float, dd.x);
            __half2 prod = __hmul2(__builtin_bit_cast(__half2, dd.y),
                                   __builtin_bit_cast(__half2, ubc));
            float b = __half2float(__low2half(prod));       // dtx*B
            float q = __half2float(__high2half(prod));      // sz*C
            float a = __builtin_amdgcn_exp2f(dtv * A2ds);
            A_run *= a;                    // running product  П a
            hB = fmaf(a, hB, b);           // local scan, h_in = 0
            W  = fmaf(A_run, q, W);        // h_in-coupling coefficient
            S  = fmaf(hB, q, S);           // h_in-independent contribution
        }

        c0 = p0; c1 = p1; c0m = p0m; c1m = p1m;
    }

    // ---- cross-segment combine (aliases dead staging LDS, post-barrier) ----
    __syncthreads();
    float2* comb = (float2*)lds;                       // 2*4*32 float2
    comb[(half*GSEG + wid)*32 + lh] = make_float2(A_run, hB);
    __syncthreads();

    // each wave composes the segments before it to get its h_in (wid uniform)
    float h_in = 0.0f;
#pragma unroll
    for (int g = 0; g < GSEG; ++g) {
        if (g < wid) {
            float2 abg = comb[(half*GSEG + g)*32 + lh];
            h_in = fmaf(abg.x, h_in, abg.y);
        }
    }

    float F = fmaf(h_in, W, S);          // this segment's Σ_t h_t q_t for (d,s)
    float tot0 = fmaf(F, owd0, sacc0);
    float tot1 = fmaf(F, owd1, sacc1);
#pragma unroll
    for (int m = 16; m >= 1; m >>= 1) {  // reduce within the 32-lane half
        tot0 += __shfl_xor(tot0, m, 64);
        tot1 += __shfl_xor(tot1, m, 64);
    }
    float* part = lds + 1024;            // past comb region (256 floats)
    if (lh == 0) {
        part[(half*GSEG + wid)*2]     = tot0;
        part[(half*GSEG + wid)*2 + 1] = tot1;
    }
    __syncthreads();

    // wave 0: sum segment partials, head projection, mean over pairs
    if (wid == 0 && lh < 16) {
        float f0 = 0.f, f1 = 0.f;
#pragma unroll
        for (int g = 0; g < GSEG; ++g) {
            f0 += part[(half*GSEG + g)*2];
            f1 += part[(half*GSEG + g)*2 + 1];
        }
        f0 *= (1.0f / (float)TT);
        f1 *= (1.0f / (float)TT);
        float pv = f0*proj_w[2*lh] + f1*proj_w[2*lh + 1] + proj_b[lh];
        pv = fmaxf(pv, 0.0f);
        atomicAdd(out + (n / NUM_PAIRS) * 16 + lh, pv * (1.0f / NUM_PAIRS));
    }
}

extern "C" void kernel_launch(void* const* d_in, const int* in_sizes, int n_in,
                              void* d_out, int out_size, void* d_ws, size_t ws_size,
                              hipStream_t stream)
{
    const float* raw        = (const float*)d_in[0];
    const float* in_proj_w  = (const float*)d_in[1];
    const float* conv_w     = (const float*)d_in[2];
    const float* conv_b     = (const float*)d_in[3];
    const float* x_proj_w   = (const float*)d_in[4];
    const float* dt_proj_w  = (const float*)d_in[5];
    const float* dt_proj_b  = (const float*)d_in[6];
    const float* A_log      = (const float*)d_in[7];
    const float* D_skip     = (const float*)d_in[8];
    const float* out_proj_w = (const float*)d_in[9];
    const float* proj_w     = (const float*)d_in[10];
    const float* proj_b     = (const float*)d_in[11];

    // d_out is re-poisoned before every timed replay; zero it (atomicAdd sink)
    hipMemsetAsync(d_out, 0, (size_t)out_size * sizeof(float), stream);

    pm_kernel<<<dim3(NSEQ / 2), dim3(256), 0, stream>>>(
        raw, in_proj_w, conv_w, conv_b, x_proj_w, dt_proj_w, dt_proj_b,
        A_log, D_skip, out_proj_w, proj_w, proj_b, (float*)d_out);
}

// Round 7
// 116.302 us; speedup vs baseline: 1.1203x; 1.1203x over previous
//
#include <hip/hip_runtime.h>
#include <hip/hip_fp16.h>

// PairwiseMamba: 2304 independent mamba scans (T=1024, d_inner=4, d_state=8).
// R6 = R4's zero-conflict staging + R5's no-spill launch bounds + 2x wave
// supply. One sequence per 256-thr block; wave w's half h owns segment
// g=2w+h of 8 segments (128 steps). 2304 blocks -> 9 blocks/CU supply vs
// 8-block residency cap -> CUs at full 32-wave occupancy in the main phase.
// Staging per (wave,half), all HW-coalesced contiguous writes (measured 0
// conflicts in R4): DT[t][d] float4, DS[t][d] uint4 half2(dtx,sz),
// BC[s][t] b32 stride 33; scan reads are b32 broadcasts on disjoint banks.
// launch_bounds(256,4): R5 proved this kills the scratch spill (WRITE 216KB).

typedef float v2f __attribute__((ext_vector_type(2)));

#define TT 1024
#define TC 32
#define NSEGS 8
#define SEGLEN (TT / NSEGS)            // 128
#define NCHUNK (SEGLEN / TC)           // 4
#define NUM_PAIRS 36
#define NSEQ 2304

// per-(wave,half) staging layout (float/uint slots):
// DT [0,128) floats, DS [128,256) uints, BC [256,520) uints
#define DT_OFF 0
#define DS_OFF 128
#define BC_OFF 256
#define BC_STRIDE 33                   // half2 slots per BC row (bank spread)
#define PER_HALF_STRIDE 528            // floats; %32==16 -> halves bank-disjoint
#define PER_WAVE (2 * PER_HALF_STRIDE) // 1056 floats
#define STAGE_TOTAL (4 * PER_WAVE)     // 4224 floats = 16896 B

__device__ __forceinline__ float fast_silu(float v) {
    float e = __builtin_amdgcn_exp2f(v * -1.4426950408889634f);
    return v * __builtin_amdgcn_rcpf(1.0f + e);
}
// softplus, direct form: log(1+exp(v)). Safe: |v| <~ 20 here.
__device__ __forceinline__ float fast_softplus(float v) {
    float e = __builtin_amdgcn_exp2f(v * 1.4426950408889634f);
    return __builtin_amdgcn_logf(1.0f + e) * 0.6931471805599453f;
}
__device__ __forceinline__ uint pk_h2(float a, float b) {
    return __builtin_bit_cast(uint, __builtin_amdgcn_cvt_pkrtz(a, b));
}

__global__ __launch_bounds__(256, 4)
void pm_kernel(const float* __restrict__ raw,        // (N,2,T)
               const float* __restrict__ in_proj_w,  // (8,2)
               const float* __restrict__ conv_w,     // (4,2)
               const float* __restrict__ conv_b,     // (4)
               const float* __restrict__ x_proj_w,   // (17,4)
               const float* __restrict__ dt_proj_w,  // (4,1)
               const float* __restrict__ dt_proj_b,  // (4)
               const float* __restrict__ A_log,      // (4,8)
               const float* __restrict__ D_skip,     // (4)
               const float* __restrict__ out_proj_w, // (2,4)
               const float* __restrict__ proj_w,     // (16,2)
               const float* __restrict__ proj_b,     // (16)
               float* __restrict__ out)              // (64,16), pre-zeroed
{
    __shared__ float lds[STAGE_TOTAL];

    const int tid  = threadIdx.x;
    const int wid  = tid >> 6;        // wave 0..3
    const int lane = tid & 63;
    const int half = lane >> 5;
    const int lh   = lane & 31;       // pointwise: t-in-chunk; scan: ds = d*8+s
    const int g    = wid * 2 + half;  // segment 0..7 of THIS block's sequence
    const int n    = blockIdx.x;      // one sequence per block
    const float* rp = raw + (size_t)n * (2 * TT);

    float* hb = lds + wid * PER_WAVE + half * PER_HALF_STRIDE;

    // ---- weights (wave-uniform -> scalarized) ----
    float ip0[8], ip1[8];
#pragma unroll
    for (int j = 0; j < 8; ++j) { ip0[j] = in_proj_w[2*j]; ip1[j] = in_proj_w[2*j+1]; }
    float cw0[4], cw1[4], cbv[4], dpw[4], dpb[4], Dsk[4], ow0[4], ow1[4], xp0[4];
#pragma unroll
    for (int d = 0; d < 4; ++d) {
        cw0[d] = conv_w[2*d]; cw1[d] = conv_w[2*d+1]; cbv[d] = conv_b[d];
        dpw[d] = dt_proj_w[d]; dpb[d] = dt_proj_b[d];
        Dsk[d] = D_skip[d]; ow0[d] = out_proj_w[d]; ow1[d] = out_proj_w[4+d];
        xp0[d] = x_proj_w[d];
    }
    v2f xbc[8][4];  // {x_proj_w[1+s][d], x_proj_w[9+s][d]}
#pragma unroll
    for (int s = 0; s < 8; ++s)
#pragma unroll
        for (int d = 0; d < 4; ++d)
            xbc[s][d] = (v2f){x_proj_w[4*(1+s) + d], x_proj_w[4*(9+s) + d]};

    const float LOG2E = 1.4426950408889634f;
    // scan-role constants: lane lh -> (d,s)
    const int   d_idx = lh >> 3;
    const int   s_idx = lh & 7;
    const float A2ds  = -__expf(A_log[lh]) * LOG2E;   // a = exp2(dt * A2ds)
    const float owd0  = out_proj_w[d_idx];
    const float owd1  = out_proj_w[4 + d_idx];

    // hoisted scan read pointers (imm offsets inside the loop)
    const float* dtp = hb + DT_OFF + d_idx;                  // [t2*4]
    const uint*  dsp = (const uint*)(hb + DS_OFF) + d_idx;   // [t2*4]
    const uint*  bcp = (const uint*)(hb + BC_OFF) + s_idx * BC_STRIDE; // [t2]

    // segment-local affine reduction state (per ds lane)
    float A_run = 1.0f, hB = 0.0f, W = 0.0f, S = 0.0f;
    float sacc0 = 0.f, sacc1 = 0.f;                    // skip-term partials

    const int seg0 = g * SEGLEN;

    // prefetch chunk 0 raw samples (t and t-1, both channels)
    int t0 = seg0 + lh;
    float c0  = rp[t0];
    float c1  = rp[TT + t0];
    float c0m = (t0 > 0) ? rp[t0 - 1]      : 0.0f;     // causal pad at t==0
    float c1m = (t0 > 0) ? rp[TT + t0 - 1] : 0.0f;

    for (int chunk = 0; chunk < NCHUNK; ++chunk) {
        // software prefetch next chunk's raw
        float p0 = 0.f, p1 = 0.f, p0m = 0.f, p1m = 0.f;
        if (chunk + 1 < NCHUNK) {
            int tn = seg0 + (chunk + 1) * TC + lh;     // tn >= 32 -> tn-1 valid
            p0  = rp[tn];       p1  = rp[TT + tn];
            p0m = rp[tn - 1];   p1m = rp[TT + tn - 1];
        }

        // ---- pointwise: this lane handles t = seg0 + chunk*TC + lh ----
        float x[4], sz[4];
#pragma unroll
        for (int d = 0; d < 4; ++d) {
            float xz  = ip0[d]*c0  + ip1[d]*c1;
            float xm1 = ip0[d]*c0m + ip1[d]*c1m;
            float zv  = ip0[4+d]*c0 + ip1[4+d]*c1;
            float v   = xm1*cw0[d] + xz*cw1[d] + cbv[d];   // causal conv k=2
            x[d]  = fast_silu(v);
            sz[d] = fast_silu(zv);
        }

        float dtin = xp0[0]*x[0] + xp0[1]*x[1] + xp0[2]*x[2] + xp0[3]*x[3];

        v2f bc[8];
#pragma unroll
        for (int s = 0; s < 8; ++s) {
            v2f a = xbc[s][0] * (v2f){x[0], x[0]};
            a = __builtin_elementwise_fma(xbc[s][1], (v2f){x[1], x[1]}, a);
            a = __builtin_elementwise_fma(xbc[s][2], (v2f){x[2], x[2]}, a);
            bc[s] = __builtin_elementwise_fma(xbc[s][3], (v2f){x[3], x[3]}, a);
        }

        float dt[4];
#pragma unroll
        for (int d = 0; d < 4; ++d) {
            dt[d] = fast_softplus(dtin*dpw[d] + dpb[d]);
            float g2 = x[d] * Dsk[d] * sz[d];              // skip term
            sacc0 = fmaf(g2, ow0[d], sacc0);
            sacc1 = fmaf(g2, ow1[d], sacc1);
        }

        // stage: DT (float4, lane-consecutive), DS (uint4), BC (8x b32)
        *(float4*)(hb + DT_OFF + lh*4) = make_float4(dt[0], dt[1], dt[2], dt[3]);
        *(uint4*)((uint*)(hb + DS_OFF) + lh*4) =
            make_uint4(pk_h2(dt[0]*x[0], sz[0]), pk_h2(dt[1]*x[1], sz[1]),
                       pk_h2(dt[2]*x[2], sz[2]), pk_h2(dt[3]*x[3], sz[3]));
        uint* bcw = (uint*)(hb + BC_OFF) + lh;
#pragma unroll
        for (int s = 0; s < 8; ++s)
            bcw[s * BC_STRIDE] = pk_h2(bc[s].x, bc[s].y);

        // ---- scan: lane owns (d_idx, s_idx); local affine reduction ----
        // (same-wave LDS RAW: compiler orders via its own waitcnt insertion)
#pragma unroll
        for (int t2 = 0; t2 < TC; ++t2) {
            float dtv = dtp[t2*4];                          // broadcast b32
            uint  uds = dsp[t2*4];                          // half2(dtx, sz)
            uint  ubc = bcp[t2];                            // half2(B, C)
            __half2 prod = __hmul2(__builtin_bit_cast(__half2, uds),
                                   __builtin_bit_cast(__half2, ubc));
            float b = __half2float(__low2half(prod));       // dtx*B
            float q = __half2float(__high2half(prod));      // sz*C
            float a = __builtin_amdgcn_exp2f(dtv * A2ds);
            A_run *= a;                    // running product  П a
            hB = fmaf(a, hB, b);           // local scan, h_in = 0
            W  = fmaf(A_run, q, W);        // h_in-coupling coefficient
            S  = fmaf(hB, q, S);           // h_in-independent contribution
        }

        c0 = p0; c1 = p1; c0m = p0m; c1m = p1m;
    }

    // ---- cross-segment combine (aliases dead staging LDS, post-barrier) ----
    __syncthreads();
    float2* comb = (float2*)lds;                       // 8*32 float2 = 512 floats
    comb[g*32 + lh] = make_float2(A_run, hB);
    __syncthreads();

    // compose the segments before g to get this segment's h_in (g wave-uniform
    // per half; exec-masked loop, max 7 iters)
    float h_in = 0.0f;
#pragma unroll
    for (int gg = 0; gg < NSEGS - 1; ++gg) {
        if (gg < g) {
            float2 abg = comb[gg*32 + lh];
            h_in = fmaf(abg.x, h_in, abg.y);
        }
    }

    float F = fmaf(h_in, W, S);          // this segment's Σ_t h_t q_t for (d,s)
    float tot0 = fmaf(F, owd0, sacc0);
    float tot1 = fmaf(F, owd1, sacc1);
#pragma unroll
    for (int m = 16; m >= 1; m >>= 1) {  // reduce within the 32-lane half
        tot0 += __shfl_xor(tot0, m, 64);
        tot1 += __shfl_xor(tot1, m, 64);
    }
    float* part = lds + 512;             // past comb region
    if (lh == 0) {
        part[g*2]     = tot0;
        part[g*2 + 1] = tot1;
    }
    __syncthreads();

    // wave 0 lanes 0-15: sum segment partials, head projection, mean over pairs
    if (tid < 16) {
        float f0 = 0.f, f1 = 0.f;
#pragma unroll
        for (int gg = 0; gg < NSEGS; ++gg) {
            f0 += part[gg*2];
            f1 += part[gg*2 + 1];
        }
        f0 *= (1.0f / (float)TT);
        f1 *= (1.0f / (float)TT);
        float pv = f0*proj_w[2*tid] + f1*proj_w[2*tid + 1] + proj_b[tid];
        pv = fmaxf(pv, 0.0f);
        atomicAdd(out + (n / NUM_PAIRS) * 16 + tid, pv * (1.0f / NUM_PAIRS));
    }
}

extern "C" void kernel_launch(void* const* d_in, const int* in_sizes, int n_in,
                              void* d_out, int out_size, void* d_ws, size_t ws_size,
                              hipStream_t stream)
{
    const float* raw        = (const float*)d_in[0];
    const float* in_proj_w  = (const float*)d_in[1];
    const float* conv_w     = (const float*)d_in[2];
    const float* conv_b     = (const float*)d_in[3];
    const float* x_proj_w   = (const float*)d_in[4];
    const float* dt_proj_w  = (const float*)d_in[5];
    const float* dt_proj_b  = (const float*)d_in[6];
    const float* A_log      = (const float*)d_in[7];
    const float* D_skip     = (const float*)d_in[8];
    const float* out_proj_w = (const float*)d_in[9];
    const float* proj_w     = (const float*)d_in[10];
    const float* proj_b     = (const float*)d_in[11];

    // d_out is re-poisoned before every timed replay; zero it (atomicAdd sink)
    hipMemsetAsync(d_out, 0, (size_t)out_size * sizeof(float), stream);

    pm_kernel<<<dim3(NSEQ), dim3(256), 0, stream>>>(
        raw, in_proj_w, conv_w, conv_b, x_proj_w, dt_proj_w, dt_proj_b,
        A_log, D_skip, out_proj_w, proj_w, proj_b, (float*)d_out);
}